// Round 1
// baseline (6423.079 us; speedup 1.0000x reference)
//
#include <hip/hip_runtime.h>
#include <hip/hip_bf16.h>
#include <math.h>

#define NN   100000
#define FIN  512
#define HH   256
#define FOUT 64

// ---------------- CSR build ----------------
__global__ void k_count(const int* __restrict__ dst, int* __restrict__ cnt, int E) {
    int i = blockIdx.x * 256 + threadIdx.x;
    if (i < E) atomicAdd(&cnt[dst[i]], 1);
}

__global__ void k_block_sums(const int* __restrict__ cnt, int* __restrict__ partial, int n) {
    __shared__ int red[256];
    int base = blockIdx.x * 1024;
    int t = threadIdx.x;
    int s = 0;
#pragma unroll
    for (int i = 0; i < 4; i++) { int idx = base + t * 4 + i; if (idx < n) s += cnt[idx]; }
    red[t] = s; __syncthreads();
    for (int off = 128; off > 0; off >>= 1) {
        if (t < off) red[t] += red[t + off];
        __syncthreads();
    }
    if (t == 0) partial[blockIdx.x] = red[0];
}

__global__ void k_scan_partials(int* partial, int nb, int* row_ptr, int n) {
    if (threadIdx.x == 0) {
        int run = 0;
        for (int i = 0; i < nb; i++) { int v = partial[i]; partial[i] = run; run += v; }
        row_ptr[n] = run;
    }
}

__global__ void k_write_rowptr(const int* __restrict__ cnt, const int* __restrict__ partial,
                               int* __restrict__ row_ptr, int* __restrict__ cur, int n) {
    __shared__ int sc[256];
    int base = blockIdx.x * 1024;
    int t = threadIdx.x;
    int v[4]; int s = 0;
#pragma unroll
    for (int i = 0; i < 4; i++) { int idx = base + t * 4 + i; v[i] = (idx < n) ? cnt[idx] : 0; s += v[i]; }
    sc[t] = s; __syncthreads();
    for (int off = 1; off < 256; off <<= 1) {
        int add = (t >= off) ? sc[t - off] : 0;
        __syncthreads();
        sc[t] += add;
        __syncthreads();
    }
    int run = partial[blockIdx.x] + sc[t] - s;  // exclusive prefix for this thread
#pragma unroll
    for (int i = 0; i < 4; i++) {
        int idx = base + t * 4 + i;
        if (idx < n) { row_ptr[idx] = run; cur[idx] = run; run += v[i]; }
    }
}

__global__ void k_dinv(const int* __restrict__ cnt, float* __restrict__ dinv, int n) {
    int i = blockIdx.x * 256 + threadIdx.x;
    if (i < n) dinv[i] = 1.0f / sqrtf((float)(cnt[i] + 1));  // +1 self loop
}

__global__ void k_scatter(const int* __restrict__ src, const int* __restrict__ dst,
                          const float* __restrict__ dinv, int* __restrict__ cur,
                          int* __restrict__ src_sorted, float* __restrict__ norm_sorted, int E) {
    int i = blockIdx.x * 256 + threadIdx.x;
    if (i < E) {
        int s = src[i], d = dst[i];
        int p = atomicAdd(&cur[d], 1);
        src_sorted[p] = s;
        norm_sorted[p] = dinv[s] * dinv[d];
    }
}

// ---------------- fp32 tiled GEMM: C[M,256] = A[M,K] @ W[K,256] (+epilogue) ----------------
// MODE 0: C = relu(AW + bias)
// MODE 1: C = relu((1-beta)*Z + beta*AW)   (Z == A, the GCNII identity mapping)
template <int K, int MODE>
__global__ __launch_bounds__(256) void k_gemm(
    const float* __restrict__ A, const float* __restrict__ W,
    const float* __restrict__ bias, const float* __restrict__ Z,
    float* __restrict__ C, int M, float beta) {
    const int N = HH;
    __shared__ float As[16][64];  // As[k][m]
    __shared__ float Bs[16][64];  // Bs[k][n]
    int tid = threadIdx.x;
    int tx = tid & 15, ty = tid >> 4;
    int bm = blockIdx.y * 64, bn = blockIdx.x * 64;
    int lm = tid >> 2, lk = (tid & 3) * 4;      // A-tile load: row lm, k-offset lk
    int lkb = tid >> 4, lnb = (tid & 15) * 4;   // B-tile load: k-row lkb, n-offset lnb
    float acc[4][4] = {};
    for (int k0 = 0; k0 < K; k0 += 16) {
        int gm = bm + lm;
        float4 av = make_float4(0.f, 0.f, 0.f, 0.f);
        if (gm < M) av = *(const float4*)&A[(size_t)gm * K + k0 + lk];
        As[lk + 0][lm] = av.x; As[lk + 1][lm] = av.y; As[lk + 2][lm] = av.z; As[lk + 3][lm] = av.w;
        *(float4*)&Bs[lkb][lnb] = *(const float4*)&W[(size_t)(k0 + lkb) * N + bn + lnb];
        __syncthreads();
#pragma unroll
        for (int k = 0; k < 16; k++) {
            float4 a = *(const float4*)&As[k][ty * 4];
            float4 b = *(const float4*)&Bs[k][tx * 4];
            acc[0][0] += a.x * b.x; acc[0][1] += a.x * b.y; acc[0][2] += a.x * b.z; acc[0][3] += a.x * b.w;
            acc[1][0] += a.y * b.x; acc[1][1] += a.y * b.y; acc[1][2] += a.y * b.z; acc[1][3] += a.y * b.w;
            acc[2][0] += a.z * b.x; acc[2][1] += a.z * b.y; acc[2][2] += a.z * b.z; acc[2][3] += a.z * b.w;
            acc[3][0] += a.w * b.x; acc[3][1] += a.w * b.y; acc[3][2] += a.w * b.z; acc[3][3] += a.w * b.w;
        }
        __syncthreads();
    }
#pragma unroll
    for (int i = 0; i < 4; i++) {
        int row = bm + ty * 4 + i;
        if (row < M) {
            int col = bn + tx * 4;
            float4 o;
            if (MODE == 0) {
                float4 bv = *(const float4*)&bias[col];
                o.x = fmaxf(acc[i][0] + bv.x, 0.f);
                o.y = fmaxf(acc[i][1] + bv.y, 0.f);
                o.z = fmaxf(acc[i][2] + bv.z, 0.f);
                o.w = fmaxf(acc[i][3] + bv.w, 0.f);
            } else {
                float4 z = *(const float4*)&Z[(size_t)row * N + col];
                float ob = 1.f - beta;
                o.x = fmaxf(ob * z.x + beta * acc[i][0], 0.f);
                o.y = fmaxf(ob * z.y + beta * acc[i][1], 0.f);
                o.z = fmaxf(ob * z.z + beta * acc[i][2], 0.f);
                o.w = fmaxf(ob * z.w + beta * acc[i][3], 0.f);
            }
            *(float4*)&C[(size_t)row * N + col] = o;
        }
    }
}

// ---------------- SpMM propagate + residual: z = 0.9*Ahat@h + 0.1*x0 ----------------
// one wave per node; lane l handles features [4l, 4l+4)
__global__ __launch_bounds__(256) void k_propagate(
    const float* __restrict__ h, const float* __restrict__ x0,
    const int* __restrict__ row_ptr, const int* __restrict__ src_sorted,
    const float* __restrict__ norm_sorted, const float* __restrict__ dinv,
    float* __restrict__ z_out) {
    int wv = threadIdx.x >> 6, lane = threadIdx.x & 63;
    int node = blockIdx.x * 4 + wv;
    if (node >= NN) return;
    int f = lane * 4;
    float di = dinv[node];
    float sw = di * di;  // self-loop weight
    float4 acc = *(const float4*)&h[(size_t)node * HH + f];
    acc.x *= sw; acc.y *= sw; acc.z *= sw; acc.w *= sw;
    int e = __builtin_amdgcn_readfirstlane(row_ptr[node]);
    int end = __builtin_amdgcn_readfirstlane(row_ptr[node + 1]);
    for (; e + 1 < end; e += 2) {
        int s0 = src_sorted[e], s1 = src_sorted[e + 1];
        float w0 = norm_sorted[e], w1 = norm_sorted[e + 1];
        float4 v0 = *(const float4*)&h[(size_t)s0 * HH + f];
        float4 v1 = *(const float4*)&h[(size_t)s1 * HH + f];
        acc.x += w0 * v0.x + w1 * v1.x;
        acc.y += w0 * v0.y + w1 * v1.y;
        acc.z += w0 * v0.z + w1 * v1.z;
        acc.w += w0 * v0.w + w1 * v1.w;
    }
    if (e < end) {
        int s0 = src_sorted[e];
        float w0 = norm_sorted[e];
        float4 v0 = *(const float4*)&h[(size_t)s0 * HH + f];
        acc.x += w0 * v0.x; acc.y += w0 * v0.y; acc.z += w0 * v0.z; acc.w += w0 * v0.w;
    }
    float4 xv = *(const float4*)&x0[(size_t)node * HH + f];
    float4 z;
    z.x = 0.9f * acc.x + 0.1f * xv.x;
    z.y = 0.9f * acc.y + 0.1f * xv.y;
    z.z = 0.9f * acc.z + 0.1f * xv.z;
    z.w = 0.9f * acc.w + 0.1f * xv.w;
    *(float4*)&z_out[(size_t)node * HH + f] = z;
}

// ---------------- final: logits/softmax/argmax, one wave per node (lane = class) ----------------
__global__ __launch_bounds__(256) void k_final(
    const float* __restrict__ h, const float* __restrict__ Wc, const float* __restrict__ bc,
    float* __restrict__ logits, float* __restrict__ soft, float* __restrict__ hard) {
    int wv = threadIdx.x >> 6, lane = threadIdx.x & 63;
    int node = blockIdx.x * 4 + wv;
    if (node >= NN) return;
    const float* hr = &h[(size_t)node * HH];
    float acc = bc[lane];
    for (int k = 0; k < HH; k += 4) {
        float4 hv = *(const float4*)&hr[k];
        acc += hv.x * Wc[(k + 0) * FOUT + lane];
        acc += hv.y * Wc[(k + 1) * FOUT + lane];
        acc += hv.z * Wc[(k + 2) * FOUT + lane];
        acc += hv.w * Wc[(k + 3) * FOUT + lane];
    }
    // softmax over 64 lanes
    float m = acc;
    for (int off = 32; off > 0; off >>= 1) m = fmaxf(m, __shfl_xor(m, off));
    float ev = expf(acc - m);
    float s = ev;
    for (int off = 32; off > 0; off >>= 1) s += __shfl_xor(s, off);
    float sm = ev / s;
    // argmax (first occurrence of max)
    int idx = lane; float v = acc;
    for (int off = 1; off < 64; off <<= 1) {
        float ov = __shfl_xor(v, off);
        int oi = __shfl_xor(idx, off);
        if (ov > v || (ov == v && oi < idx)) { v = ov; idx = oi; }
    }
    logits[(size_t)node * FOUT + lane] = acc;
    soft[(size_t)node * FOUT + lane] = sm;
    if (lane == 0) hard[node] = (float)idx;
}

extern "C" void kernel_launch(void* const* d_in, const int* in_sizes, int n_in,
                              void* d_out, int out_size, void* d_ws, size_t ws_size,
                              hipStream_t stream) {
    const float* x  = (const float*)d_in[0];
    const int*   ei = (const int*)d_in[1];
    const float* W0 = (const float*)d_in[2];
    const float* b0 = (const float*)d_in[3];
    const float* Ws = (const float*)d_in[4];
    const float* Wc = (const float*)d_in[5];
    const float* bc = (const float*)d_in[6];
    const int E = in_sizes[1] / 2;
    const int N = in_sizes[0] / FIN;
    const int L = in_sizes[4] / (HH * HH);

    float* out    = (float*)d_out;
    float* logits = out;                          // [N,64]
    float* emb    = out + (size_t)N * FOUT;       // [N,256] — also the h ping buffer
    float* soft   = emb + (size_t)N * HH;         // [N,64]
    float* hard   = soft + (size_t)N * FOUT;      // [N]

    char* p = (char*)d_ws;
    size_t off = 0;
    auto alloc = [&](size_t bytes) { void* r = p + off; off += (bytes + 255) & ~(size_t)255; return r; };
    int*   cnt         = (int*)alloc((size_t)N * 4);
    int*   row_ptr     = (int*)alloc((size_t)(N + 1) * 4);
    int*   cur         = (int*)alloc((size_t)N * 4);
    int*   partial     = (int*)alloc(4096 * 4);
    float* dinv        = (float*)alloc((size_t)N * 4);
    int*   src_sorted  = (int*)alloc((size_t)E * 4);
    float* norm_sorted = (float*)alloc((size_t)E * 4);
    float* X0          = (float*)alloc((size_t)N * HH * 4);
    float* A           = (float*)alloc((size_t)N * HH * 4);

    const int* srcp = ei;
    const int* dstp = ei + E;

    hipMemsetAsync(cnt, 0, (size_t)N * 4, stream);
    k_count<<<(E + 255) / 256, 256, 0, stream>>>(dstp, cnt, E);
    const int nb = (N + 1023) / 1024;
    k_block_sums<<<nb, 256, 0, stream>>>(cnt, partial, N);
    k_scan_partials<<<1, 64, 0, stream>>>(partial, nb, row_ptr, N);
    k_write_rowptr<<<nb, 256, 0, stream>>>(cnt, partial, row_ptr, cur, N);
    k_dinv<<<(N + 255) / 256, 256, 0, stream>>>(cnt, dinv, N);
    k_scatter<<<(E + 255) / 256, 256, 0, stream>>>(srcp, dstp, dinv, cur, src_sorted, norm_sorted, E);

    dim3 gg(HH / 64, (N + 63) / 64);
    k_gemm<FIN, 0><<<gg, 256, 0, stream>>>(x, W0, b0, nullptr, X0, N, 0.f);

    const float* h = X0;  // h0 == x0 (read-only; X0 preserved for residuals)
    for (int i = 0; i < L; i++) {
        float beta = (float)log(0.5 / (i + 1) + 1.0);
        k_propagate<<<(N + 3) / 4, 256, 0, stream>>>(h, X0, row_ptr, src_sorted, norm_sorted, dinv, A);
        k_gemm<HH, 1><<<gg, 256, 0, stream>>>(A, Ws + (size_t)i * HH * HH, nullptr, A, emb, N, beta);
        h = emb;
    }
    k_final<<<(N + 3) / 4, 256, 0, stream>>>(emb, Wc, bc, logits, soft, hard);
}

// Round 2
// 5724.975 us; speedup vs baseline: 1.1219x; 1.1219x over previous
//
#include <hip/hip_runtime.h>
#include <hip/hip_bf16.h>
#include <math.h>

#define NN   100000
#define FIN  512
#define HH   256
#define FOUT 64

typedef __attribute__((ext_vector_type(8))) short s16x8;
typedef __attribute__((ext_vector_type(4))) float f32x4;

// ---------------- CSR build ----------------
__global__ void k_count(const int* __restrict__ dst, int* __restrict__ cnt, int E) {
    int i = blockIdx.x * 256 + threadIdx.x;
    if (i < E) atomicAdd(&cnt[dst[i]], 1);
}

__global__ void k_block_sums(const int* __restrict__ cnt, int* __restrict__ partial, int n) {
    __shared__ int red[256];
    int base = blockIdx.x * 1024;
    int t = threadIdx.x;
    int s = 0;
#pragma unroll
    for (int i = 0; i < 4; i++) { int idx = base + t * 4 + i; if (idx < n) s += cnt[idx]; }
    red[t] = s; __syncthreads();
    for (int off = 128; off > 0; off >>= 1) {
        if (t < off) red[t] += red[t + off];
        __syncthreads();
    }
    if (t == 0) partial[blockIdx.x] = red[0];
}

__global__ void k_scan_partials(int* partial, int nb, int* row_ptr, int n) {
    if (threadIdx.x == 0) {
        int run = 0;
        for (int i = 0; i < nb; i++) { int v = partial[i]; partial[i] = run; run += v; }
        row_ptr[n] = run;
    }
}

__global__ void k_write_rowptr(const int* __restrict__ cnt, const int* __restrict__ partial,
                               int* __restrict__ row_ptr, int* __restrict__ cur, int n) {
    __shared__ int sc[256];
    int base = blockIdx.x * 1024;
    int t = threadIdx.x;
    int v[4]; int s = 0;
#pragma unroll
    for (int i = 0; i < 4; i++) { int idx = base + t * 4 + i; v[i] = (idx < n) ? cnt[idx] : 0; s += v[i]; }
    sc[t] = s; __syncthreads();
    for (int off = 1; off < 256; off <<= 1) {
        int add = (t >= off) ? sc[t - off] : 0;
        __syncthreads();
        sc[t] += add;
        __syncthreads();
    }
    int run = partial[blockIdx.x] + sc[t] - s;
#pragma unroll
    for (int i = 0; i < 4; i++) {
        int idx = base + t * 4 + i;
        if (idx < n) { row_ptr[idx] = run; cur[idx] = run; run += v[i]; }
    }
}

__global__ void k_dinv(const int* __restrict__ cnt, float* __restrict__ dinv, int n) {
    int i = blockIdx.x * 256 + threadIdx.x;
    if (i < n) dinv[i] = 1.0f / sqrtf((float)(cnt[i] + 1));
}

__global__ void k_scatter(const int* __restrict__ src, const int* __restrict__ dst,
                          const float* __restrict__ dinv, int* __restrict__ cur,
                          int* __restrict__ src_sorted, float* __restrict__ norm_sorted, int E) {
    int i = blockIdx.x * 256 + threadIdx.x;
    if (i < E) {
        int s = src[i], d = dst[i];
        int p = atomicAdd(&cur[d], 1);
        src_sorted[p] = s;
        norm_sorted[p] = dinv[s] * dinv[d];
    }
}

// ---------------- bf16 split helpers ----------------
__device__ __forceinline__ short f2bf_rn(float f) {
    unsigned b = __float_as_uint(f);
    unsigned r = b + 0x7FFFu + ((b >> 16) & 1u);
    return (short)(r >> 16);
}
__device__ __forceinline__ float bf2f(short h) {
    return __uint_as_float(((unsigned)(unsigned short)h) << 16);
}
__device__ __forceinline__ void split_bf16(float f, short& hi, short& lo) {
    hi = f2bf_rn(f);
    lo = f2bf_rn(f - bf2f(hi));
}

// ---------------- weight prep: fp32 [K][256] -> fragment-chunk bf16 hi/lo ----------------
// chunk ci = kt*1024 + nt*64 + g*16 + colin ; holds W[kt*32+g*8+j][nt*16+colin], j=0..7
__global__ void k_wprep(const float* __restrict__ W, short* __restrict__ whi,
                        short* __restrict__ wlo, int K) {
    int t = blockIdx.x * 256 + threadIdx.x;
    int total = K * HH / 8;
    if (t >= total) return;
    int colin = t & 15, g = (t >> 4) & 3, nt = (t >> 6) & 15, kt = t >> 10;
    int col = nt * 16 + colin, kb = kt * 32 + g * 8;
    s16x8 h8, l8;
#pragma unroll
    for (int j = 0; j < 8; j++) {
        float f = W[(size_t)(kb + j) * HH + col];
        short h, l; split_bf16(f, h, l);
        h8[j] = h; l8[j] = l;
    }
    *(s16x8*)&whi[(size_t)t * 8] = h8;
    *(s16x8*)&wlo[(size_t)t * 8] = l8;
}

// ---------------- split-bf16 MFMA GEMM: C[M,256] = A[M,K] @ W[K,256] + epilogue ----------------
// MODE 0: C = relu(AW + bias) ; MODE 1: C = relu((1-beta)*Z + beta*AW)
template <int K, int MODE>
__global__ __launch_bounds__(256) void k_mgemm(
    const float* __restrict__ A, const short* __restrict__ Whi, const short* __restrict__ Wlo,
    const float* __restrict__ bias, const float* __restrict__ Z,
    float* __restrict__ C, int M, float beta) {
    // LDS: A tile 64x32 as bf16 hi/lo in fragment-chunk order (swizzled)
    __shared__ short As_hi[2048];
    __shared__ short As_lo[2048];
    int tid = threadIdx.x;
    int lane = tid & 63, wid = tid >> 6;
    int wm = wid >> 1, wn = wid & 1;
    int bm = blockIdx.y * 64, bn = blockIdx.x * 64;

    // staging role: thread t -> row=t>>2, kl=(t&3)*8 ; chunk (row, g=t&3)
    int st_row = tid >> 2, st_g = tid & 3;
    int st_cphys = ((st_row & 15) ^ ((st_g & 1) << 2)) + 16 * st_g + 64 * (st_row >> 4);
    const float* st_ap = A + (size_t)(bm + st_row) * K + st_g * 8;
    bool st_ok = (bm + st_row) < M;

    // fragment-read addresses (lane-constant): row&15 = lane&15, g = lane>>4
    int fr_g = lane >> 4, fr_r = lane & 15;
    int fr_base = (fr_r ^ ((fr_g & 1) << 2)) + 16 * fr_g;  // + 64*(wm*2+rt)
    int c0 = (fr_base + 64 * (wm * 2 + 0)) * 8;
    int c1 = (fr_base + 64 * (wm * 2 + 1)) * 8;

    // B chunk lane offset within a 16-col tile: g*16 + colin
    int lane_off = fr_g * 16 + fr_r;
    int ntbase = (bn >> 4) + wn * 2;

    f32x4 acc[2][2] = {};

    for (int k0 = 0; k0 < K; k0 += 32) {
        // ---- stage A tile: fp32 -> hi/lo bf16 chunks in LDS ----
        float4 v0 = make_float4(0.f, 0.f, 0.f, 0.f), v1 = v0;
        if (st_ok) {
            v0 = *(const float4*)(st_ap + k0);
            v1 = *(const float4*)(st_ap + k0 + 4);
        }
        s16x8 h8, l8;
        {
            float f[8] = {v0.x, v0.y, v0.z, v0.w, v1.x, v1.y, v1.z, v1.w};
#pragma unroll
            for (int j = 0; j < 8; j++) { short h, l; split_bf16(f[j], h, l); h8[j] = h; l8[j] = l; }
        }
        *(s16x8*)&As_hi[st_cphys * 8] = h8;
        *(s16x8*)&As_lo[st_cphys * 8] = l8;
        __syncthreads();

        // ---- B fragments direct from prepped global (L2-resident) ----
        int kt = k0 >> 5;
        size_t btile = (size_t)kt * 1024 + (size_t)ntbase * 64;
        s16x8 bh0 = *(const s16x8*)&Whi[(btile + lane_off) * 8];
        s16x8 bl0 = *(const s16x8*)&Wlo[(btile + lane_off) * 8];
        s16x8 bh1 = *(const s16x8*)&Whi[(btile + 64 + lane_off) * 8];
        s16x8 bl1 = *(const s16x8*)&Wlo[(btile + 64 + lane_off) * 8];

        // ---- A fragments from LDS ----
        s16x8 ah0 = *(const s16x8*)&As_hi[c0];
        s16x8 al0 = *(const s16x8*)&As_lo[c0];
        s16x8 ah1 = *(const s16x8*)&As_hi[c1];
        s16x8 al1 = *(const s16x8*)&As_lo[c1];

        // ---- 12 MFMAs: hi*hi + hi*lo + lo*hi ----
        acc[0][0] = __builtin_amdgcn_mfma_f32_16x16x32_bf16(ah0, bh0, acc[0][0], 0, 0, 0);
        acc[0][1] = __builtin_amdgcn_mfma_f32_16x16x32_bf16(ah0, bh1, acc[0][1], 0, 0, 0);
        acc[1][0] = __builtin_amdgcn_mfma_f32_16x16x32_bf16(ah1, bh0, acc[1][0], 0, 0, 0);
        acc[1][1] = __builtin_amdgcn_mfma_f32_16x16x32_bf16(ah1, bh1, acc[1][1], 0, 0, 0);
        acc[0][0] = __builtin_amdgcn_mfma_f32_16x16x32_bf16(ah0, bl0, acc[0][0], 0, 0, 0);
        acc[0][1] = __builtin_amdgcn_mfma_f32_16x16x32_bf16(ah0, bl1, acc[0][1], 0, 0, 0);
        acc[1][0] = __builtin_amdgcn_mfma_f32_16x16x32_bf16(ah1, bl0, acc[1][0], 0, 0, 0);
        acc[1][1] = __builtin_amdgcn_mfma_f32_16x16x32_bf16(ah1, bl1, acc[1][1], 0, 0, 0);
        acc[0][0] = __builtin_amdgcn_mfma_f32_16x16x32_bf16(al0, bh0, acc[0][0], 0, 0, 0);
        acc[0][1] = __builtin_amdgcn_mfma_f32_16x16x32_bf16(al0, bh1, acc[0][1], 0, 0, 0);
        acc[1][0] = __builtin_amdgcn_mfma_f32_16x16x32_bf16(al1, bh0, acc[1][0], 0, 0, 0);
        acc[1][1] = __builtin_amdgcn_mfma_f32_16x16x32_bf16(al1, bh1, acc[1][1], 0, 0, 0);
        __syncthreads();
    }

    // ---- epilogue: D row = (lane>>4)*4+reg, col = lane&15 (within 16x16 tile) ----
    int rsub = (lane >> 4) * 4, csub = lane & 15;
#pragma unroll
    for (int rt = 0; rt < 2; rt++) {
#pragma unroll
        for (int ct = 0; ct < 2; ct++) {
            int col = bn + wn * 32 + ct * 16 + csub;
            int r0 = bm + wm * 32 + rt * 16 + rsub;
#pragma unroll
            for (int reg = 0; reg < 4; reg++) {
                int row = r0 + reg;
                if (row < M) {
                    size_t idx = (size_t)row * HH + col;
                    float a = acc[rt][ct][reg];
                    float o;
                    if (MODE == 0) o = fmaxf(a + bias[col], 0.f);
                    else {
                        float z = Z[idx];
                        o = fmaxf((1.f - beta) * z + beta * a, 0.f);
                    }
                    C[idx] = o;
                }
            }
        }
    }
}

// ---------------- SpMM propagate + residual: z = 0.9*Ahat@h + 0.1*x0 ----------------
__global__ __launch_bounds__(256) void k_propagate(
    const float* __restrict__ h, const float* __restrict__ x0,
    const int* __restrict__ row_ptr, const int* __restrict__ src_sorted,
    const float* __restrict__ norm_sorted, const float* __restrict__ dinv,
    float* __restrict__ z_out) {
    int wv = threadIdx.x >> 6, lane = threadIdx.x & 63;
    int node = blockIdx.x * 4 + wv;
    if (node >= NN) return;
    int f = lane * 4;
    float di = dinv[node];
    float sw = di * di;
    float4 acc = *(const float4*)&h[(size_t)node * HH + f];
    acc.x *= sw; acc.y *= sw; acc.z *= sw; acc.w *= sw;
    int e = __builtin_amdgcn_readfirstlane(row_ptr[node]);
    int end = __builtin_amdgcn_readfirstlane(row_ptr[node + 1]);
    // 4-deep unroll: 4 outstanding 1KB gathers per wave
    for (; e + 3 < end; e += 4) {
        int s0 = src_sorted[e], s1 = src_sorted[e + 1], s2 = src_sorted[e + 2], s3 = src_sorted[e + 3];
        float w0 = norm_sorted[e], w1 = norm_sorted[e + 1], w2 = norm_sorted[e + 2], w3 = norm_sorted[e + 3];
        float4 v0 = *(const float4*)&h[(size_t)s0 * HH + f];
        float4 v1 = *(const float4*)&h[(size_t)s1 * HH + f];
        float4 v2 = *(const float4*)&h[(size_t)s2 * HH + f];
        float4 v3 = *(const float4*)&h[(size_t)s3 * HH + f];
        acc.x += w0 * v0.x + w1 * v1.x + w2 * v2.x + w3 * v3.x;
        acc.y += w0 * v0.y + w1 * v1.y + w2 * v2.y + w3 * v3.y;
        acc.z += w0 * v0.z + w1 * v1.z + w2 * v2.z + w3 * v3.z;
        acc.w += w0 * v0.w + w1 * v1.w + w2 * v2.w + w3 * v3.w;
    }
    for (; e < end; e++) {
        int s0 = src_sorted[e];
        float w0 = norm_sorted[e];
        float4 v0 = *(const float4*)&h[(size_t)s0 * HH + f];
        acc.x += w0 * v0.x; acc.y += w0 * v0.y; acc.z += w0 * v0.z; acc.w += w0 * v0.w;
    }
    float4 xv = *(const float4*)&x0[(size_t)node * HH + f];
    float4 z;
    z.x = 0.9f * acc.x + 0.1f * xv.x;
    z.y = 0.9f * acc.y + 0.1f * xv.y;
    z.z = 0.9f * acc.z + 0.1f * xv.z;
    z.w = 0.9f * acc.w + 0.1f * xv.w;
    *(float4*)&z_out[(size_t)node * HH + f] = z;
}

// ---------------- final: logits/softmax/argmax ----------------
__global__ __launch_bounds__(256) void k_final(
    const float* __restrict__ h, const float* __restrict__ Wc, const float* __restrict__ bc,
    float* __restrict__ logits, float* __restrict__ soft, float* __restrict__ hard) {
    int wv = threadIdx.x >> 6, lane = threadIdx.x & 63;
    int node = blockIdx.x * 4 + wv;
    if (node >= NN) return;
    const float* hr = &h[(size_t)node * HH];
    float acc = bc[lane];
    for (int k = 0; k < HH; k += 4) {
        float4 hv = *(const float4*)&hr[k];
        acc += hv.x * Wc[(k + 0) * FOUT + lane];
        acc += hv.y * Wc[(k + 1) * FOUT + lane];
        acc += hv.z * Wc[(k + 2) * FOUT + lane];
        acc += hv.w * Wc[(k + 3) * FOUT + lane];
    }
    float m = acc;
    for (int off = 32; off > 0; off >>= 1) m = fmaxf(m, __shfl_xor(m, off));
    float ev = expf(acc - m);
    float s = ev;
    for (int off = 32; off > 0; off >>= 1) s += __shfl_xor(s, off);
    float sm = ev / s;
    int idx = lane; float v = acc;
    for (int off = 1; off < 64; off <<= 1) {
        float ov = __shfl_xor(v, off);
        int oi = __shfl_xor(idx, off);
        if (ov > v || (ov == v && oi < idx)) { v = ov; idx = oi; }
    }
    logits[(size_t)node * FOUT + lane] = acc;
    soft[(size_t)node * FOUT + lane] = sm;
    if (lane == 0) hard[node] = (float)idx;
}

extern "C" void kernel_launch(void* const* d_in, const int* in_sizes, int n_in,
                              void* d_out, int out_size, void* d_ws, size_t ws_size,
                              hipStream_t stream) {
    const float* x  = (const float*)d_in[0];
    const int*   ei = (const int*)d_in[1];
    const float* W0 = (const float*)d_in[2];
    const float* b0 = (const float*)d_in[3];
    const float* Ws = (const float*)d_in[4];
    const float* Wc = (const float*)d_in[5];
    const float* bc = (const float*)d_in[6];
    const int E = in_sizes[1] / 2;
    const int N = in_sizes[0] / FIN;
    const int L = in_sizes[4] / (HH * HH);

    float* out    = (float*)d_out;
    float* logits = out;
    float* emb    = out + (size_t)N * FOUT;
    float* soft   = emb + (size_t)N * HH;
    float* hard   = soft + (size_t)N * FOUT;

    char* p = (char*)d_ws;
    size_t off = 0;
    auto alloc = [&](size_t bytes) { void* r = p + off; off += (bytes + 255) & ~(size_t)255; return r; };
    int*   cnt         = (int*)alloc((size_t)N * 4);
    int*   row_ptr     = (int*)alloc((size_t)(N + 1) * 4);
    int*   cur         = (int*)alloc((size_t)N * 4);
    int*   partial     = (int*)alloc(4096 * 4);
    float* dinv        = (float*)alloc((size_t)N * 4);
    int*   src_sorted  = (int*)alloc((size_t)E * 4);
    float* norm_sorted = (float*)alloc((size_t)E * 4);
    float* X0          = (float*)alloc((size_t)N * HH * 4);
    float* A           = (float*)alloc((size_t)N * HH * 4);
    short* W0hi        = (short*)alloc((size_t)FIN * HH * 2);
    short* W0lo        = (short*)alloc((size_t)FIN * HH * 2);
    short* Wshi        = (short*)alloc((size_t)L * HH * HH * 2);
    short* Wslo        = (short*)alloc((size_t)L * HH * HH * 2);

    const int* srcp = ei;
    const int* dstp = ei + E;

    hipMemsetAsync(cnt, 0, (size_t)N * 4, stream);
    k_count<<<(E + 255) / 256, 256, 0, stream>>>(dstp, cnt, E);
    const int nb = (N + 1023) / 1024;
    k_block_sums<<<nb, 256, 0, stream>>>(cnt, partial, N);
    k_scan_partials<<<1, 64, 0, stream>>>(partial, nb, row_ptr, N);
    k_write_rowptr<<<nb, 256, 0, stream>>>(cnt, partial, row_ptr, cur, N);
    k_dinv<<<(N + 255) / 256, 256, 0, stream>>>(cnt, dinv, N);
    k_scatter<<<(E + 255) / 256, 256, 0, stream>>>(srcp, dstp, dinv, cur, src_sorted, norm_sorted, E);

    // weight prep (runs every launch; deterministic)
    k_wprep<<<(FIN * HH / 8 + 255) / 256, 256, 0, stream>>>(W0, W0hi, W0lo, FIN);
    for (int i = 0; i < L; i++)
        k_wprep<<<(HH * HH / 8 + 255) / 256, 256, 0, stream>>>(
            Ws + (size_t)i * HH * HH, Wshi + (size_t)i * HH * HH, Wslo + (size_t)i * HH * HH, HH);

    dim3 gg(HH / 64, (N + 63) / 64);
    k_mgemm<FIN, 0><<<gg, 256, 0, stream>>>(x, W0hi, W0lo, b0, nullptr, X0, N, 0.f);

    const float* h = X0;
    for (int i = 0; i < L; i++) {
        float beta = (float)log(0.5 / (i + 1) + 1.0);
        k_propagate<<<(N + 3) / 4, 256, 0, stream>>>(h, X0, row_ptr, src_sorted, norm_sorted, dinv, A);
        k_mgemm<HH, 1><<<gg, 256, 0, stream>>>(A, Wshi + (size_t)i * HH * HH, Wslo + (size_t)i * HH * HH,
                                               nullptr, A, emb, N, beta);
        h = emb;
    }
    k_final<<<(N + 3) / 4, 256, 0, stream>>>(emb, Wc, bc, logits, soft, hard);
}